// Round 3
// baseline (203.161 us; speedup 1.0000x reference)
//
#include <hip/hip_runtime.h>
#include <hip/hip_cooperative_groups.h>

namespace cg = cooperative_groups;

// NeighborList: N atoms, minimum-image convention, cutoff 5.0.
// Output layout (all float32): pairs[2*P], deltas[P*3], distances[P], n_pairs[1]
// Ordering must match jnp.nonzero(mask.ravel()) -> ascending flat index i*N+j.
//
// Single cooperative kernel: pad + count(+in-register masks) + grid.sync()
// + per-wave prefix over counts + ordered fill. One wave per row; with
// N=4096, nchunks = N/64 = 64 = wave width, so lane c holds chunk c's
// 64-bit hit mask in a register across the sync -- no mask workspace.

#define CUT2 25.0f

__device__ __forceinline__ void load_box_inv(const float* __restrict__ box,
                                             float B[3][3], float Binv[3][3]) {
    #pragma unroll
    for (int r = 0; r < 3; ++r)
        #pragma unroll
        for (int c = 0; c < 3; ++c)
            B[r][c] = box[r * 3 + c];

    float a00 = B[0][0], a01 = B[0][1], a02 = B[0][2];
    float a10 = B[1][0], a11 = B[1][1], a12 = B[1][2];
    float a20 = B[2][0], a21 = B[2][1], a22 = B[2][2];

    float adj00 =  (a11 * a22 - a12 * a21);
    float adj01 = -(a01 * a22 - a02 * a21);
    float adj02 =  (a01 * a12 - a02 * a11);
    float adj10 = -(a10 * a22 - a12 * a20);
    float adj11 =  (a00 * a22 - a02 * a20);
    float adj12 = -(a00 * a12 - a02 * a10);
    float adj20 =  (a10 * a21 - a11 * a20);
    float adj21 = -(a00 * a21 - a01 * a20);
    float adj22 =  (a00 * a11 - a01 * a10);

    float det = a00 * adj00 + a01 * adj10 + a02 * adj20;

    // per-entry division: for diagonal box this rounds identically to
    // LAPACK's 1/pivot (single rounding of the exact quotient).
    Binv[0][0] = __fdiv_rn(adj00, det); Binv[0][1] = __fdiv_rn(adj01, det); Binv[0][2] = __fdiv_rn(adj02, det);
    Binv[1][0] = __fdiv_rn(adj10, det); Binv[1][1] = __fdiv_rn(adj11, det); Binv[1][2] = __fdiv_rn(adj12, det);
    Binv[2][0] = __fdiv_rn(adj20, det); Binv[2][1] = __fdiv_rn(adj21, det); Binv[2][2] = __fdiv_rn(adj22, det);
}

// Replicates numpy rounding exactly (no FMA contraction):
// delta = pos_i - pos_j; frac = delta @ Binv; delta -= rint(frac) @ B; d2 = sum(delta^2)
__device__ __forceinline__ void min_image(float xi, float yi, float zi,
                                          float xj, float yj, float zj,
                                          const float B[3][3], const float Binv[3][3],
                                          float& dx, float& dy, float& dz, float& d2) {
    dx = __fsub_rn(xi, xj);
    dy = __fsub_rn(yi, yj);
    dz = __fsub_rn(zi, zj);

    float f0 = __fadd_rn(__fadd_rn(__fmul_rn(dx, Binv[0][0]), __fmul_rn(dy, Binv[1][0])), __fmul_rn(dz, Binv[2][0]));
    float f1 = __fadd_rn(__fadd_rn(__fmul_rn(dx, Binv[0][1]), __fmul_rn(dy, Binv[1][1])), __fmul_rn(dz, Binv[2][1]));
    float f2 = __fadd_rn(__fadd_rn(__fmul_rn(dx, Binv[0][2]), __fmul_rn(dy, Binv[1][2])), __fmul_rn(dz, Binv[2][2]));

    float r0 = rintf(f0), r1 = rintf(f1), r2 = rintf(f2);

    float c0 = __fadd_rn(__fadd_rn(__fmul_rn(r0, B[0][0]), __fmul_rn(r1, B[1][0])), __fmul_rn(r2, B[2][0]));
    float c1 = __fadd_rn(__fadd_rn(__fmul_rn(r0, B[0][1]), __fmul_rn(r1, B[1][1])), __fmul_rn(r2, B[2][1]));
    float c2 = __fadd_rn(__fadd_rn(__fmul_rn(r0, B[0][2]), __fmul_rn(r1, B[1][2])), __fmul_rn(r2, B[2][2]));

    dx = __fsub_rn(dx, c0);
    dy = __fsub_rn(dy, c1);
    dz = __fsub_rn(dz, c2);

    d2 = __fadd_rn(__fadd_rn(__fmul_rn(dx, dx), __fmul_rn(dy, dy)), __fmul_rn(dz, dz));
}

__global__ void __launch_bounds__(256, 4)
nl_fused_kernel(const float* __restrict__ pos, const float* __restrict__ box,
                float* __restrict__ out, int* __restrict__ counts, int N, int P) {
    cg::grid_group grid = cg::this_grid();

    int tid = blockIdx.x * blockDim.x + threadIdx.x;
    int nthreads = gridDim.x * blockDim.x;   // == N * 64 / 64 waves * 64
    int i = tid >> 6;                        // row (one wave per row)
    int lane = tid & 63;
    int nchunks = N >> 6;                    // 64 (== wave width)
    int c0 = i >> 6;                         // first chunk with any j > i

    // ---- Phase 0: pad output (pairs = -1, rest = 0) ----
    int total = 6 * P + 1;
    for (int k = tid; k < total; k += nthreads)
        out[k] = (k < 2 * P) ? -1.0f : 0.0f;

    // ---- Phase 1: count + in-register per-chunk masks ----
    float B[3][3], Binv[3][3];
    load_box_inv(box, B, Binv);

    float xi = pos[3 * i + 0], yi = pos[3 * i + 1], zi = pos[3 * i + 2];

    unsigned long long mymask = 0ull;   // lane c holds chunk c's mask
    int cnt = 0;

    // Diagonal chunk: needs the j>i predicate.
    {
        int j = (c0 << 6) + lane;
        bool hit = false;
        if (j > i) {
            float dx, dy, dz, d2;
            min_image(xi, yi, zi, pos[3 * j + 0], pos[3 * j + 1], pos[3 * j + 2],
                      B, Binv, dx, dy, dz, d2);
            hit = (d2 < CUT2);
        }
        unsigned long long m = __ballot(hit);
        if (lane == c0) mymask = m;
        cnt += __popcll(m);
    }

    // Remaining chunks: all j > i. Unroll x2 for ILP.
    int c = c0 + 1;
    for (; c + 2 <= nchunks; c += 2) {
        int j0 = (c << 6) + lane;
        int j1 = j0 + 64;
        float dx0, dy0, dz0, d20, dx1, dy1, dz1, d21;
        min_image(xi, yi, zi, pos[3 * j0 + 0], pos[3 * j0 + 1], pos[3 * j0 + 2],
                  B, Binv, dx0, dy0, dz0, d20);
        min_image(xi, yi, zi, pos[3 * j1 + 0], pos[3 * j1 + 1], pos[3 * j1 + 2],
                  B, Binv, dx1, dy1, dz1, d21);
        unsigned long long m0 = __ballot(d20 < CUT2);
        unsigned long long m1 = __ballot(d21 < CUT2);
        if (lane == c)     mymask = m0;
        if (lane == c + 1) mymask = m1;
        cnt += __popcll(m0) + __popcll(m1);
    }
    if (c < nchunks) {
        int j = (c << 6) + lane;
        float dx, dy, dz, d2;
        min_image(xi, yi, zi, pos[3 * j + 0], pos[3 * j + 1], pos[3 * j + 2],
                  B, Binv, dx, dy, dz, d2);
        unsigned long long m = __ballot(d2 < CUT2);
        if (lane == c) mymask = m;
        cnt += __popcll(m);
    }

    if (lane == 0) counts[i] = cnt;

    // ---- Phase 2: grid-wide barrier (orders counts[] and pad writes) ----
    grid.sync();

    // ---- Phase 3: per-wave exclusive prefix of counts[0..i) ----
    int pre = 0;
    for (int b = 0; b < i; b += 64) {
        int k = b + lane;
        pre += (k < i) ? counts[k] : 0;
    }
    #pragma unroll
    for (int d = 1; d < 64; d <<= 1)
        pre += __shfl_xor(pre, d);          // all lanes hold sum(counts[0..i))

    if (i == N - 1 && lane == 0)
        out[6 * (size_t)P] = (float)(pre + cnt);   // n_pairs

    // ---- Phase 4: ordered fill from in-register masks ----
    int base = pre;
    for (int cc = c0; cc < nchunks; ++cc) {
        unsigned long long m = __shfl(mymask, cc);
        if (m != 0ull) {
            if ((m >> lane) & 1ull) {
                int j = (cc << 6) + lane;
                float dx, dy, dz, d2;
                min_image(xi, yi, zi, pos[3 * j + 0], pos[3 * j + 1], pos[3 * j + 2],
                          B, Binv, dx, dy, dz, d2);
                int slot = base + __popcll(m & ((1ull << lane) - 1ull));
                if (slot < P) {
                    out[slot] = (float)i;                    // pair_i
                    out[P + slot] = (float)j;                // pair_j
                    size_t db = 2 * (size_t)P + 3 * (size_t)slot;
                    out[db + 0] = dx;
                    out[db + 1] = dy;
                    out[db + 2] = dz;
                    out[5 * (size_t)P + slot] = sqrtf(d2);   // distance
                }
            }
            base += __popcll(m);
        }
    }
}

extern "C" void kernel_launch(void* const* d_in, const int* in_sizes, int n_in,
                              void* d_out, int out_size, void* d_ws, size_t ws_size,
                              hipStream_t stream) {
    const float* pos = (const float*)d_in[0];
    const float* box = (const float*)d_in[1];
    float* out = (float*)d_out;

    int N = in_sizes[0] / 3;          // 4096
    int P = (out_size - 1) / 6;       // 131072

    int* counts = (int*)d_ws;         // N ints

    // One wave per row: N*64 threads = N/4 blocks of 256.
    dim3 grid(N / 4), block(256);
    void* args[] = {(void*)&pos, (void*)&box, (void*)&out, (void*)&counts,
                    (void*)&N, (void*)&P};
    hipLaunchCooperativeKernel((const void*)nl_fused_kernel, grid, block,
                               args, 0, stream);
}

// Round 4
// 95.707 us; speedup vs baseline: 2.1227x; 2.1227x over previous
//
#include <hip/hip_runtime.h>

// NeighborList: N atoms, minimum-image convention, cutoff 5.0.
// Output layout (all float32): pairs[2*P], deltas[P*3], distances[P], n_pairs[1]
// Ordering must match jnp.nonzero(mask.ravel()) -> ascending flat index i*N+j.
//
// Two dispatches (cooperative grid.sync measured 100+us on this chip -- avoid):
//  K1: pad output + per-row count + per-chunk 64-bit hit masks (row-paired
//      waves (w, N-1-w) for deterministic load balance).
//  K2: per-wave inline exclusive prefix over counts[] + ordered fill from masks.

#define CUT2 25.0f

__device__ __forceinline__ void load_box_inv(const float* __restrict__ box,
                                             float B[3][3], float Binv[3][3]) {
    #pragma unroll
    for (int r = 0; r < 3; ++r)
        #pragma unroll
        for (int c = 0; c < 3; ++c)
            B[r][c] = box[r * 3 + c];

    float a00 = B[0][0], a01 = B[0][1], a02 = B[0][2];
    float a10 = B[1][0], a11 = B[1][1], a12 = B[1][2];
    float a20 = B[2][0], a21 = B[2][1], a22 = B[2][2];

    float adj00 =  (a11 * a22 - a12 * a21);
    float adj01 = -(a01 * a22 - a02 * a21);
    float adj02 =  (a01 * a12 - a02 * a11);
    float adj10 = -(a10 * a22 - a12 * a20);
    float adj11 =  (a00 * a22 - a02 * a20);
    float adj12 = -(a00 * a12 - a02 * a10);
    float adj20 =  (a10 * a21 - a11 * a20);
    float adj21 = -(a00 * a21 - a01 * a20);
    float adj22 =  (a00 * a11 - a01 * a10);

    float det = a00 * adj00 + a01 * adj10 + a02 * adj20;

    // per-entry division: for diagonal box this rounds identically to
    // LAPACK's 1/pivot (single rounding of the exact quotient).
    Binv[0][0] = __fdiv_rn(adj00, det); Binv[0][1] = __fdiv_rn(adj01, det); Binv[0][2] = __fdiv_rn(adj02, det);
    Binv[1][0] = __fdiv_rn(adj10, det); Binv[1][1] = __fdiv_rn(adj11, det); Binv[1][2] = __fdiv_rn(adj12, det);
    Binv[2][0] = __fdiv_rn(adj20, det); Binv[2][1] = __fdiv_rn(adj21, det); Binv[2][2] = __fdiv_rn(adj22, det);
}

// Replicates numpy rounding exactly (no FMA contraction):
// delta = pos_i - pos_j; frac = delta @ Binv; delta -= rint(frac) @ B; d2 = sum(delta^2)
__device__ __forceinline__ void min_image(float xi, float yi, float zi,
                                          float xj, float yj, float zj,
                                          const float B[3][3], const float Binv[3][3],
                                          float& dx, float& dy, float& dz, float& d2) {
    dx = __fsub_rn(xi, xj);
    dy = __fsub_rn(yi, yj);
    dz = __fsub_rn(zi, zj);

    float f0 = __fadd_rn(__fadd_rn(__fmul_rn(dx, Binv[0][0]), __fmul_rn(dy, Binv[1][0])), __fmul_rn(dz, Binv[2][0]));
    float f1 = __fadd_rn(__fadd_rn(__fmul_rn(dx, Binv[0][1]), __fmul_rn(dy, Binv[1][1])), __fmul_rn(dz, Binv[2][1]));
    float f2 = __fadd_rn(__fadd_rn(__fmul_rn(dx, Binv[0][2]), __fmul_rn(dy, Binv[1][2])), __fmul_rn(dz, Binv[2][2]));

    float r0 = rintf(f0), r1 = rintf(f1), r2 = rintf(f2);

    float c0 = __fadd_rn(__fadd_rn(__fmul_rn(r0, B[0][0]), __fmul_rn(r1, B[1][0])), __fmul_rn(r2, B[2][0]));
    float c1 = __fadd_rn(__fadd_rn(__fmul_rn(r0, B[0][1]), __fmul_rn(r1, B[1][1])), __fmul_rn(r2, B[2][1]));
    float c2 = __fadd_rn(__fadd_rn(__fmul_rn(r0, B[0][2]), __fmul_rn(r1, B[1][2])), __fmul_rn(r2, B[2][2]));

    dx = __fsub_rn(dx, c0);
    dy = __fsub_rn(dy, c1);
    dz = __fsub_rn(dz, c2);

    d2 = __fadd_rn(__fadd_rn(__fmul_rn(dx, dx), __fmul_rn(dy, dy)), __fmul_rn(dz, dz));
}

// Count hits for row i (j > i), writing per-chunk 64-bit masks to mrow[].
__device__ __forceinline__ int count_row(int i, int lane,
                                         const float* __restrict__ pos,
                                         const float B[3][3], const float Binv[3][3],
                                         unsigned long long* __restrict__ mrow,
                                         int nchunks) {
    float xi = pos[3 * i + 0], yi = pos[3 * i + 1], zi = pos[3 * i + 2];
    int c0 = i >> 6;
    int cnt = 0;

    // Diagonal chunk: needs the j>i predicate.
    {
        int j = (c0 << 6) + lane;
        bool hit = false;
        if (j > i) {
            float dx, dy, dz, d2;
            min_image(xi, yi, zi, pos[3 * j + 0], pos[3 * j + 1], pos[3 * j + 2],
                      B, Binv, dx, dy, dz, d2);
            hit = (d2 < CUT2);
        }
        unsigned long long m = __ballot(hit);
        if (lane == 0) mrow[c0] = m;
        cnt += __popcll(m);
    }

    // Remaining chunks: all j > i. Unroll x2 for ILP.
    int c = c0 + 1;
    for (; c + 2 <= nchunks; c += 2) {
        int j0 = (c << 6) + lane;
        int j1 = j0 + 64;
        float dx0, dy0, dz0, d20, dx1, dy1, dz1, d21;
        min_image(xi, yi, zi, pos[3 * j0 + 0], pos[3 * j0 + 1], pos[3 * j0 + 2],
                  B, Binv, dx0, dy0, dz0, d20);
        min_image(xi, yi, zi, pos[3 * j1 + 0], pos[3 * j1 + 1], pos[3 * j1 + 2],
                  B, Binv, dx1, dy1, dz1, d21);
        unsigned long long m0 = __ballot(d20 < CUT2);
        unsigned long long m1 = __ballot(d21 < CUT2);
        if (lane == 0) { mrow[c] = m0; mrow[c + 1] = m1; }
        cnt += __popcll(m0) + __popcll(m1);
    }
    if (c < nchunks) {
        int j = (c << 6) + lane;
        float dx, dy, dz, d2;
        min_image(xi, yi, zi, pos[3 * j + 0], pos[3 * j + 1], pos[3 * j + 2],
                  B, Binv, dx, dy, dz, d2);
        unsigned long long m = __ballot(d2 < CUT2);
        if (lane == 0) mrow[c] = m;
        cnt += __popcll(m);
    }
    return cnt;
}

// K1: pad output + count rows (w, N-1-w) per wave + write masks.
__global__ void __launch_bounds__(256)
k1_pad_count(const float* __restrict__ pos, const float* __restrict__ box,
             float* __restrict__ out, int* __restrict__ counts,
             unsigned long long* __restrict__ masks, int N, int P) {
    int tid = blockIdx.x * blockDim.x + threadIdx.x;
    int nthreads = gridDim.x * blockDim.x;   // (N/2)*64

    // pad: pairs = -1, rest = 0
    int total = 6 * P + 1;
    for (int k = tid; k < total; k += nthreads)
        out[k] = (k < 2 * P) ? -1.0f : 0.0f;

    int w = tid >> 6;
    int lane = tid & 63;
    int nchunks = N >> 6;

    float B[3][3], Binv[3][3];
    load_box_inv(box, B, Binv);

    int rowA = w;            // heavy row (many chunks)
    int rowB = N - 1 - w;    // light row -> balanced total per wave

    int cA = count_row(rowA, lane, pos, B, Binv,
                       masks + (size_t)rowA * nchunks, nchunks);
    if (lane == 0) counts[rowA] = cA;

    int cB = count_row(rowB, lane, pos, B, Binv,
                       masks + (size_t)rowB * nchunks, nchunks);
    if (lane == 0) counts[rowB] = cB;
}

// K2: one wave per row. Inline exclusive prefix over counts[0..i), then
// ordered fill of hits from the precomputed masks.
__global__ void __launch_bounds__(256)
k2_scan_fill(const float* __restrict__ pos, const float* __restrict__ box,
             const int* __restrict__ counts,
             const unsigned long long* __restrict__ masks,
             float* __restrict__ out, int N, int P) {
    int tid = blockIdx.x * blockDim.x + threadIdx.x;
    int i = tid >> 6;
    int lane = tid & 63;
    int nchunks = N >> 6;
    int c0 = i >> 6;

    // Exclusive prefix: sum counts[0..i) across the wave, butterfly-reduce.
    int pre = 0;
    for (int b = 0; b < i; b += 64) {
        int k = b + lane;
        pre += (k < i) ? counts[k] : 0;
    }
    #pragma unroll
    for (int d = 1; d < 64; d <<= 1)
        pre += __shfl_xor(pre, d);           // all lanes: sum(counts[0..i))

    if (i == N - 1 && lane == 0)
        out[6 * (size_t)P] = (float)(pre + counts[i]);   // n_pairs

    // lane l holds the mask of chunk l for this row (only cc >= c0 consumed).
    unsigned long long mymask = masks[(size_t)i * nchunks + lane];

    float B[3][3], Binv[3][3];
    load_box_inv(box, B, Binv);
    float xi = pos[3 * i + 0], yi = pos[3 * i + 1], zi = pos[3 * i + 2];

    int base = pre;
    for (int cc = c0; cc < nchunks; ++cc) {
        unsigned long long m = __shfl(mymask, cc);
        if (m != 0ull) {
            if ((m >> lane) & 1ull) {
                int j = (cc << 6) + lane;
                float dx, dy, dz, d2;
                min_image(xi, yi, zi, pos[3 * j + 0], pos[3 * j + 1], pos[3 * j + 2],
                          B, Binv, dx, dy, dz, d2);
                int slot = base + __popcll(m & ((1ull << lane) - 1ull));
                if (slot < P) {
                    out[slot] = (float)i;                    // pair_i
                    out[P + slot] = (float)j;                // pair_j
                    size_t db = 2 * (size_t)P + 3 * (size_t)slot;
                    out[db + 0] = dx;
                    out[db + 1] = dy;
                    out[db + 2] = dz;
                    out[5 * (size_t)P + slot] = sqrtf(d2);   // distance
                }
            }
            base += __popcll(m);
        }
    }
}

extern "C" void kernel_launch(void* const* d_in, const int* in_sizes, int n_in,
                              void* d_out, int out_size, void* d_ws, size_t ws_size,
                              hipStream_t stream) {
    const float* pos = (const float*)d_in[0];
    const float* box = (const float*)d_in[1];
    float* out = (float*)d_out;

    int N = in_sizes[0] / 3;          // 4096
    int P = (out_size - 1) / 6;       // 131072
    int nchunks = N >> 6;

    // ws layout: counts[N] | masks[N*nchunks]
    char* w = (char*)d_ws;
    int* counts = (int*)w;                         w += (size_t)N * sizeof(int);
    unsigned long long* masks = (unsigned long long*)w;

    // K1: one wave per row-pair -> N/2 waves -> N/8 blocks of 256.
    k1_pad_count<<<N / 8, 256, 0, stream>>>(pos, box, out, counts, masks, N, P);

    // K2: one wave per row -> N/4 blocks of 256.
    k2_scan_fill<<<N / 4, 256, 0, stream>>>(pos, box, counts, masks, out, N, P);
}